// Round 8
// baseline (291.919 us; speedup 1.0000x reference)
//
#include <hip/hip_runtime.h>
#include <hip/hip_bf16.h>
#include <hip/hip_cooperative_groups.h>

namespace cg = cooperative_groups;

typedef __attribute__((ext_vector_type(8))) __bf16 bf16x8;
typedef __attribute__((ext_vector_type(4))) __bf16 bf16x4;
typedef __attribute__((ext_vector_type(4))) float  f32x4;

// ---------------------------------------------------------------------------
// async global->LDS, 16B per lane. LDS dest must be wave-uniform base.
__device__ __forceinline__ void gl_lds16(const __bf16* g, __bf16* l) {
  __builtin_amdgcn_global_load_lds(
      (const __attribute__((address_space(1))) void*)g,
      (__attribute__((address_space(3))) void*)l,
      16, 0, 0);
}

// ---------------------------------------------------------------------------
// Merged prep: role-switched by block range.
//   [0,64)        : Wq^T  f32->bf16 (LDS-tiled transpose)
//   [64,128)      : Wv^T
//   [128,384)     : Wc    f2bf
//   [384,2432)    : genT  (gen 512x2047 -> 2048x512 bf16, row 2047 zero)
//   [2432,10624)  : x     f2bf
//   [10624,11128) : g2t partials (f32 exact path)
__global__ __launch_bounds__(256) void prep_kernel(
    const float* __restrict__ x, const float* __restrict__ gen,
    const float* __restrict__ Wq, const float* __restrict__ Wv, const float* __restrict__ Wc,
    __bf16* __restrict__ xb, __bf16* __restrict__ genT,
    __bf16* __restrict__ wqT, __bf16* __restrict__ wvT, __bf16* __restrict__ wcb,
    float* __restrict__ gp) {
  __shared__ float S[64][65];
  const int blk = blockIdx.x, tid = threadIdx.x;

  if (blk < 128) { // transposes
    const float* in = (blk < 64) ? Wq : Wv;
    __bf16* out = (blk < 64) ? wqT : wvT;
    int t = blk & 63;
    int tx = tid & 63, ty = tid >> 6;
    int d0 = (t >> 3) * 64, e0 = (t & 7) * 64;
#pragma unroll
    for (int i = 0; i < 16; ++i) {
      int di = i * 4 + ty;
      S[di][tx] = in[(long)(d0 + di) * 512 + e0 + tx];
    }
    __syncthreads();
#pragma unroll
    for (int i = 0; i < 16; ++i) {
      int ei = i * 4 + ty;
      out[(long)(e0 + ei) * 512 + d0 + tx] = (__bf16)S[tx][ei];
    }
  } else if (blk < 384) { // Wc f2bf
    int i = (blk - 128) * 256 + tid;
    float4 v = ((const float4*)Wc)[i];
    bf16x4 o;
    o[0] = (__bf16)v.x; o[1] = (__bf16)v.y; o[2] = (__bf16)v.z; o[3] = (__bf16)v.w;
    *(bf16x4*)(wcb + 4L * i) = o;
  } else if (blk < 2432) { // genT
    int i = blk - 384;
    for (int d = tid; d < 512; d += 256) {
      float v = (i < 2047) ? gen[(long)d * 2047 + i] : 0.f;
      genT[(long)i * 512 + d] = (__bf16)v;
    }
  } else if (blk < 10624) { // x f2bf
    int i = (blk - 2432) * 256 + tid;
    float4 v = ((const float4*)x)[i];
    bf16x4 o;
    o[0] = (__bf16)v.x; o[1] = (__bf16)v.y; o[2] = (__bf16)v.z; o[3] = (__bf16)v.w;
    *(bf16x4*)(xb + 4L * i) = o;
  } else { // g2t partials
    int t = blk - 10624;       // 0..503
    int i = t % 63, c = t / 63;
    int d0 = c * 64, k = tid;
    float a0 = 0.f, a1 = 0.f;
#pragma unroll 8
    for (int u = 0; u < 64; ++u) {
      int d = d0 + u;
      float g = gen[(long)d * 2047 + 992 + i];
      a0 += Wq[(long)d * 512 + k] * g;
      a1 += Wq[(long)d * 512 + k + 256] * g;
    }
    long o = ((long)c * 63 + i) * 512;
    gp[o + k] = a0;
    gp[o + k + 256] = a1;
  }
}

__global__ void g2t_reduce(const float* __restrict__ gp, float* __restrict__ g2t) {
  int idx = blockIdx.x * 256 + threadIdx.x; // 0..32255
  if (idx >= 63 * 512) return;
  float s = 0.f;
#pragma unroll
  for (int c = 0; c < 8; ++c) s += gp[(long)c * 63 * 512 + idx];
  g2t[idx] = s;
}

// ---------------------------------------------------------------------------
// bf16 GEMM, C = A @ B^T. 128x128 tile, BK=32, 4 waves.
// Counted-vmcnt 2-deep pipeline (T4): stage t+1 stays in flight across barriers.
// MODE 1: store bf16 C. MODE 4: f32 C scaled by 1/(aux[row]+1e-8).
// TRIL: A lower-triangular in K -> K-loop ends at m0+128.
template <int MODE, bool TRIL = false>
__global__ __launch_bounds__(256) void gemm_bt(
    const __bf16* __restrict__ A, const __bf16* __restrict__ B, void* __restrict__ Cv,
    const float* __restrict__ aux, int N, int K, long sA, long sB, long sC, int sAux) {
  __shared__ __bf16 As[2][128 * 32];
  __shared__ __bf16 Bs[2][128 * 32];
  const int tid = threadIdx.x;
  const int w = tid >> 6, l = tid & 63;
  const int m0 = blockIdx.y * 128;
  const int n0 = blockIdx.x * 128;
  const int bz = blockIdx.z;
  const __bf16* Ab = A + (long)bz * sA;
  const __bf16* Bb = B + (long)bz * sB;

  const int srow = w * 16 + (l >> 2);
  const int scol = (l & 3) * 8;
  const int wr = (w >> 1) * 64, wc = (w & 1) * 64;
  const int fr = l & 15, fk = (l >> 4) * 8;

  f32x4 acc[4][4] = {};

  const int KM = TRIL ? min(K, m0 + 128) : K;
  const int nt = KM >> 5;

  auto STAGE = [&](int t, int p) {
    const int k0 = t << 5;
    gl_lds16(Ab + (long)(m0 + srow) * K + (k0 + scol),      &As[p][(w * 16) * 32]);
    gl_lds16(Ab + (long)(m0 + 64 + srow) * K + (k0 + scol), &As[p][(64 + w * 16) * 32]);
    gl_lds16(Bb + (long)(n0 + srow) * K + (k0 + scol),      &Bs[p][(w * 16) * 32]);
    gl_lds16(Bb + (long)(n0 + 64 + srow) * K + (k0 + scol), &Bs[p][(64 + w * 16) * 32]);
  };

  STAGE(0, 0);
  STAGE(1, 1);

  for (int t = 0; t < nt; ++t) {
    if (t == nt - 1) asm volatile("s_waitcnt vmcnt(0)\ns_barrier" ::: "memory");
    else             asm volatile("s_waitcnt vmcnt(4)\ns_barrier" ::: "memory");
    const int p = t & 1;
    bf16x8 af[4], bg[4];
#pragma unroll
    for (int i = 0; i < 4; ++i) af[i] = *(const bf16x8*)&As[p][(wr + i * 16 + fr) * 32 + fk];
#pragma unroll
    for (int j = 0; j < 4; ++j) bg[j] = *(const bf16x8*)&Bs[p][(wc + j * 16 + fr) * 32 + fk];
    asm volatile("s_waitcnt lgkmcnt(0)\ns_barrier" ::: "memory");
    if (t + 2 < nt) STAGE(t + 2, p);
#pragma unroll
    for (int i = 0; i < 4; ++i)
#pragma unroll
      for (int j = 0; j < 4; ++j)
        acc[i][j] = __builtin_amdgcn_mfma_f32_16x16x32_bf16(af[i], bg[j], acc[i][j], 0, 0, 0);
  }

  const int rbase = m0 + wr + ((l >> 4) << 2);
  const int cbase = n0 + wc + fr;

  if constexpr (MODE == 1) {
    __bf16* C = (__bf16*)Cv + (long)bz * sC;
#pragma unroll
    for (int i = 0; i < 4; ++i)
#pragma unroll
      for (int r = 0; r < 4; ++r) {
        long row = rbase + i * 16 + r;
#pragma unroll
        for (int j = 0; j < 4; ++j) C[row * N + cbase + j * 16] = (__bf16)acc[i][j][r];
      }
  } else { // MODE 4
    float* C = (float*)Cv + (long)bz * sC;
    const float* ax = aux + (long)bz * sAux;
#pragma unroll
    for (int i = 0; i < 4; ++i)
#pragma unroll
      for (int r = 0; r < 4; ++r) {
        long row = rbase + i * 16 + r;
        float sc = 1.f / (ax[row] + 1e-8f);
#pragma unroll
        for (int j = 0; j < 4; ++j) C[row * N + cbase + j * 16] = acc[i][j][r] * sc;
      }
  }
}

// ---------------------------------------------------------------------------
// Merged x-GEMM, counted-vmcnt 2-deep pipeline. A = xb (16384 x 512).
//   xt in [0,9):  band tile vs Bg  -> gathered S[row][jj], jj = col-1023+(row&1023)
//   xt in [9,13): vT tile vs Pmat -> vT[(row>>10)*512 + col][row&1023]
// XCD-swizzled linear grid: 1664 = 8 * 208 blocks.
__global__ __launch_bounds__(256) void gemm_x(
    const __bf16* __restrict__ A, const __bf16* __restrict__ Bg,
    const __bf16* __restrict__ Pm, __bf16* __restrict__ S, __bf16* __restrict__ vT) {
  __shared__ __bf16 As[2][128 * 32];
  __shared__ __bf16 Bs[2][128 * 32];
  const int tid = threadIdx.x;
  const int w = tid >> 6, l = tid & 63;

  int wgid = blockIdx.x;
  int swz = (wgid & 7) * 208 + (wgid >> 3);
  int y = swz / 13, xt = swz - y * 13;
  const bool band = (xt < 9);
  const int m0 = y * 128;
  const int n0 = band ? (7 - (y & 7) + xt) * 128 : (xt - 9) * 128;
  const __bf16* Bb = band ? Bg : Pm;
  const int K = 512;

  const int srow = w * 16 + (l >> 2);
  const int scol = (l & 3) * 8;
  const int wr = (w >> 1) * 64, wc = (w & 1) * 64;
  const int fr = l & 15, fk = (l >> 4) * 8;

  f32x4 acc[4][4] = {};

  auto STAGE = [&](int t, int p) {
    const int k0 = t << 5;
    gl_lds16(A + (long)(m0 + srow) * K + (k0 + scol),       &As[p][(w * 16) * 32]);
    gl_lds16(A + (long)(m0 + 64 + srow) * K + (k0 + scol),  &As[p][(64 + w * 16) * 32]);
    gl_lds16(Bb + (long)(n0 + srow) * K + (k0 + scol),      &Bs[p][(w * 16) * 32]);
    gl_lds16(Bb + (long)(n0 + 64 + srow) * K + (k0 + scol), &Bs[p][(64 + w * 16) * 32]);
  };

  STAGE(0, 0);
  STAGE(1, 1);

  for (int t = 0; t < 16; ++t) {
    if (t == 15) asm volatile("s_waitcnt vmcnt(0)\ns_barrier" ::: "memory");
    else         asm volatile("s_waitcnt vmcnt(4)\ns_barrier" ::: "memory");
    const int p = t & 1;
    bf16x8 af[4], bg[4];
#pragma unroll
    for (int i = 0; i < 4; ++i) af[i] = *(const bf16x8*)&As[p][(wr + i * 16 + fr) * 32 + fk];
#pragma unroll
    for (int j = 0; j < 4; ++j) bg[j] = *(const bf16x8*)&Bs[p][(wc + j * 16 + fr) * 32 + fk];
    asm volatile("s_waitcnt lgkmcnt(0)\ns_barrier" ::: "memory");
    if (t + 2 < 16) STAGE(t + 2, p);
#pragma unroll
    for (int i = 0; i < 4; ++i)
#pragma unroll
      for (int j = 0; j < 4; ++j)
        acc[i][j] = __builtin_amdgcn_mfma_f32_16x16x32_bf16(af[i], bg[j], acc[i][j], 0, 0, 0);
  }

  const int rbase = m0 + wr + ((l >> 4) << 2);
  const int cbase = n0 + wc + fr;

  if (band) {
#pragma unroll
    for (int i = 0; i < 4; ++i)
#pragma unroll
      for (int r = 0; r < 4; ++r) {
        int row = rbase + i * 16 + r;
        int lloc = row & 1023;
#pragma unroll
        for (int j = 0; j < 4; ++j) {
          int jj = cbase + j * 16 - 1023 + lloc;
          if ((unsigned)jj < 1024u)
            S[(long)row * 1024 + jj] = (__bf16)acc[i][j][r];
        }
      }
  } else {
#pragma unroll
    for (int i = 0; i < 4; ++i) {
      int gm = rbase + i * 16;
      int bt = gm >> 10, lloc = gm & 1023;
#pragma unroll
      for (int j = 0; j < 4; ++j) {
        bf16x4 pk;
        pk[0] = (__bf16)acc[i][j][0]; pk[1] = (__bf16)acc[i][j][1];
        pk[2] = (__bf16)acc[i][j][2]; pk[3] = (__bf16)acc[i][j][3];
        *(bf16x4*)&vT[((long)bt * 512 + cbase + j * 16) * 1024 + lloc] = pk;
      }
    }
  }
}

// ---------------------------------------------------------------------------
// Cooperative fused scan: 512 blocks (b in [0,16), c in [0,32)), 256 threads.
// Phase A: stage 32x1024 chunk of S in LDS, column partial sums -> csum; c==1 zeros rsum.
// Phase B (c==0): per-b exclusive scan of 32 chunk sums per column.
// Phase C: walk LDS chunk with offsets, relu/tril, store wrelu, rowsum atomics.
__global__ __launch_bounds__(256) void scan_fused(
    const __bf16* __restrict__ S, float* __restrict__ csum,
    __bf16* __restrict__ wrelu, float* __restrict__ rowsum) {
  cg::grid_group grid = cg::this_grid();
  __shared__ __bf16 Sl[32 * 1024]; // 64 KiB
  const int blk = blockIdx.x, tid = threadIdx.x;
  const int b = blk >> 5, c = blk & 31;
  const __bf16* Sb = S + ((long)b * 1024 + c * 32) * 1024;

  for (int e = tid; e < 32 * 128; e += 256) {
    int row = e >> 7, c8 = (e & 127) * 8;
    *(bf16x8*)&Sl[row * 1024 + c8] = *(const bf16x8*)&Sb[(long)row * 1024 + c8];
  }
  if (c == 1) {
    for (int i = tid; i < 1024; i += 256) rowsum[b * 1024 + i] = 0.f;
  }
  __syncthreads();
  {
    int j0 = tid * 4;
    float a0 = 0.f, a1 = 0.f, a2 = 0.f, a3 = 0.f;
    for (int l = 0; l < 32; ++l) {
      bf16x4 v = *(const bf16x4*)&Sl[l * 1024 + j0];
      a0 += (float)v[0]; a1 += (float)v[1]; a2 += (float)v[2]; a3 += (float)v[3];
    }
    long o = ((long)(b * 32 + c) << 10) + j0;
    csum[o] = a0; csum[o + 1] = a1; csum[o + 2] = a2; csum[o + 3] = a3;
  }
  grid.sync();
  if (c == 0) {
    for (int j = tid; j < 1024; j += 256) {
      long base = ((long)b * 32 << 10) + j;
      float s = 0.f;
      for (int cc = 0; cc < 32; ++cc) {
        long o = base + ((long)cc << 10);
        float t = csum[o]; csum[o] = s; s += t;
      }
    }
  }
  grid.sync();
  {
    int j0 = tid * 4;
    long co = ((long)(b * 32 + c) << 10) + j0;
    float r0 = csum[co], r1 = csum[co + 1], r2 = csum[co + 2], r3 = csum[co + 3];
    __bf16* wr = wrelu + ((long)b * 1024 + c * 32) * 1024;
    const int l0 = c * 32;
    for (int l = 0; l < 32; ++l) {
      bf16x4 v = *(const bf16x4*)&Sl[l * 1024 + j0];
      r0 += (float)v[0]; r1 += (float)v[1]; r2 += (float)v[2]; r3 += (float)v[3];
      int gl = l0 + l;
      float v0 = (j0     <= gl) ? fmaxf(r0, 0.f) : 0.f;
      float v1 = (j0 + 1 <= gl) ? fmaxf(r1, 0.f) : 0.f;
      float v2 = (j0 + 2 <= gl) ? fmaxf(r2, 0.f) : 0.f;
      float v3 = (j0 + 3 <= gl) ? fmaxf(r3, 0.f) : 0.f;
      bf16x4 o4;
      o4[0] = (__bf16)v0; o4[1] = (__bf16)v1; o4[2] = (__bf16)v2; o4[3] = (__bf16)v3;
      *(bf16x4*)&wr[(long)l * 1024 + j0] = o4;
      float rs = v0 + v1 + v2 + v3;
#pragma unroll
      for (int off = 32; off; off >>= 1) rs += __shfl_down(rs, off);
      if ((tid & 63) == 0 && rs != 0.f) atomicAdd(&rowsum[b * 1024 + gl], rs);
    }
  }
}

// ---------------------------------------------------------------------------
// Exact f32 path for rows l<32 (sign-flip hazard region).
__global__ __launch_bounds__(256) void small_dots(
    const float* __restrict__ x, const float* __restrict__ g2t, float* __restrict__ S) {
  int gid = blockIdx.x * 4 + (threadIdx.x >> 6); // 0..16383
  int lane = threadIdx.x & 63;
  int b = gid >> 10, rem = gid & 1023, m = rem >> 5, j = rem & 31;
  const float4* xr = (const float4*)(x + ((long)b * 1024 + m) * 512);
  const float4* gr = (const float4*)(g2t + (long)(31 - m + j) * 512);
  float4 a0 = xr[lane * 2], a1 = xr[lane * 2 + 1];
  float4 c0 = gr[lane * 2], c1 = gr[lane * 2 + 1];
  float s = a0.x * c0.x + a0.y * c0.y + a0.z * c0.z + a0.w * c0.w
          + a1.x * c1.x + a1.y * c1.y + a1.z * c1.z + a1.w * c1.w;
#pragma unroll
  for (int off = 32; off; off >>= 1) s += __shfl_down(s, off);
  if (lane == 0) S[gid] = s;
}

__global__ __launch_bounds__(1024) void small_scan(
    const float* __restrict__ Sg, __bf16* __restrict__ wrelu, float* __restrict__ rowsum) {
  int b = blockIdx.x, tid = threadIdx.x;
  __shared__ float S[32][33];
  int m = tid >> 5, j = tid & 31;
  S[m][j] = Sg[b * 1024 + tid];
  __syncthreads();
  if (tid < 32) {
    float run = 0.f;
    for (int mm = 0; mm < 32; ++mm) { run += S[mm][tid]; S[mm][tid] = run; }
  }
  __syncthreads();
  float v = (j <= m) ? fmaxf(S[m][j], 0.f) : 0.f;
  wrelu[((long)b * 1024 + m) * 1024 + j] = (__bf16)v;
  float rs = v;
#pragma unroll
  for (int off = 16; off; off >>= 1) rs += __shfl_down(rs, off, 32);
  if (j == 0) rowsum[b * 1024 + m] = rs;
}

// ---------------------------------------------------------------------------
extern "C" void kernel_launch(void* const* d_in, const int* in_sizes, int n_in,
                              void* d_out, int out_size, void* d_ws, size_t ws_size,
                              hipStream_t stream) {
  const float* x   = (const float*)d_in[0];
  const float* gen = (const float*)d_in[1];
  const float* Wq  = (const float*)d_in[2];
  const float* Wv  = (const float*)d_in[3];
  const float* Wc  = (const float*)d_in[4];

  char* ws = (char*)d_ws;
  __bf16* xb    = (__bf16*)(ws + 0L);
  __bf16* vT    = (__bf16*)(ws + 33554432L);
  __bf16* Smat  = (__bf16*)(ws + 67108864L);   // gathered scores, 32 MiB
  __bf16* wrelu = (__bf16*)(ws + 134217728L);
  __bf16* genT  = (__bf16*)(ws + 167772160L);
  __bf16* wqT   = (__bf16*)(ws + 169869312L);
  __bf16* wvT   = (__bf16*)(ws + 170393600L);
  __bf16* wcb   = (__bf16*)(ws + 170917888L);
  float*  g2t   = (float*)(ws + 171442176L);
  // overlays in the free region at 16 MiB:
  float*  csum  = (float*)(ws + 16777216L);            // 2 MiB
  float*  rsum  = (float*)(ws + 16777216L + 2097152L); // 64 KiB
  float*  Sbuf  = (float*)(ws + 16777216L + 2162688L); // 64 KiB
  // overlays in the free region at 48 MiB:
  __bf16* Pmat  = (__bf16*)(ws + 50331648L);           // 512x512 bf16 (Wc@Wv)
  __bf16* Bg    = (__bf16*)(ws + 51380224L);           // 2048x512 bf16 (gen^T@Wq^T)
  float*  gp    = (float*)(ws + 58720256L);            // 1 MiB g2t partials

  // merged prep: transposes + f2bf (Wc, x) + genT + g2t partials
  prep_kernel<<<11128, 256, 0, stream>>>(x, gen, Wq, Wv, Wc, xb, genT, wqT, wvT, wcb, gp);
  g2t_reduce<<<126, 256, 0, stream>>>(gp, g2t);

  // Weight folding: P = Wc@Wv, Bg = gen^T@Wq^T
  gemm_bt<1><<<dim3(4, 4, 1), 256, 0, stream>>>(wcb, wvT, Pmat, nullptr, 512, 512, 0, 0, 0, 0);
  gemm_bt<1><<<dim3(4, 16, 1), 256, 0, stream>>>(genT, wqT, Bg, nullptr, 512, 512, 0, 0, 0, 0);

  // merged: gathered S = band(x@Bg^T) ; vT = (x@P^T)^T   (XCD-swizzled, counted-vmcnt)
  gemm_x<<<1664, 256, 0, stream>>>(xb, Bg, Pmat, Smat, vT);

  // cooperative fused scan: chunk sums + exclusive scan + relu/tril + rowsum
  {
    const __bf16* Sp = Smat; float* cs = csum; __bf16* wr = wrelu; float* rs = rsum;
    void* args[] = { (void*)&Sp, (void*)&cs, (void*)&wr, (void*)&rs };
    hipLaunchCooperativeKernel((const void*)scan_fused, dim3(512), dim3(256), args, 0, stream);
  }

  // exact f32 fix for rows l<32
  small_dots<<<4096, 256, 0, stream>>>(x, g2t, Sbuf);
  small_scan<<<16, 1024, 0, stream>>>(Sbuf, wrelu, rsum);

  // OUT = normalize(Wrelu) @ vc  (batched, triangular) -> f32 d_out directly
  gemm_bt<4, true><<<dim3(4, 8, 16), 256, 0, stream>>>(wrelu, vT, d_out, rsum, 512, 1024,
                                                 1024L * 1024, 512L * 1024, 512L * 1024, 1024);
}

// Round 9
// 159.197 us; speedup vs baseline: 1.8337x; 1.8337x over previous
//
#include <hip/hip_runtime.h>
#include <hip/hip_bf16.h>

typedef __attribute__((ext_vector_type(8))) __bf16 bf16x8;
typedef __attribute__((ext_vector_type(4))) __bf16 bf16x4;
typedef __attribute__((ext_vector_type(4))) float  f32x4;

// ---------------------------------------------------------------------------
// async global->LDS, 16B per lane. LDS dest must be wave-uniform base.
__device__ __forceinline__ void gl_lds16(const __bf16* g, __bf16* l) {
  __builtin_amdgcn_global_load_lds(
      (const __attribute__((address_space(1))) void*)g,
      (__attribute__((address_space(3))) void*)l,
      16, 0, 0);
}

// ---------------------------------------------------------------------------
// Merged prep: role-switched by block range.
//   [0,64)        : Wq^T  f32->bf16 (LDS-tiled transpose)
//   [64,128)      : Wv^T
//   [128,384)     : Wc    f2bf
//   [384,2432)    : genT  (gen 512x2047 -> 2048x512 bf16, row 2047 zero)
//   [2432,10624)  : x     f2bf
//   [10624,11128) : g2t partials (f32 exact path)
__global__ __launch_bounds__(256) void prep_kernel(
    const float* __restrict__ x, const float* __restrict__ gen,
    const float* __restrict__ Wq, const float* __restrict__ Wv, const float* __restrict__ Wc,
    __bf16* __restrict__ xb, __bf16* __restrict__ genT,
    __bf16* __restrict__ wqT, __bf16* __restrict__ wvT, __bf16* __restrict__ wcb,
    float* __restrict__ gp) {
  __shared__ float S[64][65];
  const int blk = blockIdx.x, tid = threadIdx.x;

  if (blk < 128) { // transposes
    const float* in = (blk < 64) ? Wq : Wv;
    __bf16* out = (blk < 64) ? wqT : wvT;
    int t = blk & 63;
    int tx = tid & 63, ty = tid >> 6;
    int d0 = (t >> 3) * 64, e0 = (t & 7) * 64;
#pragma unroll
    for (int i = 0; i < 16; ++i) {
      int di = i * 4 + ty;
      S[di][tx] = in[(long)(d0 + di) * 512 + e0 + tx];
    }
    __syncthreads();
#pragma unroll
    for (int i = 0; i < 16; ++i) {
      int ei = i * 4 + ty;
      out[(long)(e0 + ei) * 512 + d0 + tx] = (__bf16)S[tx][ei];
    }
  } else if (blk < 384) { // Wc f2bf
    int i = (blk - 128) * 256 + tid;
    float4 v = ((const float4*)Wc)[i];
    bf16x4 o;
    o[0] = (__bf16)v.x; o[1] = (__bf16)v.y; o[2] = (__bf16)v.z; o[3] = (__bf16)v.w;
    *(bf16x4*)(wcb + 4L * i) = o;
  } else if (blk < 2432) { // genT
    int i = blk - 384;
    for (int d = tid; d < 512; d += 256) {
      float v = (i < 2047) ? gen[(long)d * 2047 + i] : 0.f;
      genT[(long)i * 512 + d] = (__bf16)v;
    }
  } else if (blk < 10624) { // x f2bf
    int i = (blk - 2432) * 256 + tid;
    float4 v = ((const float4*)x)[i];
    bf16x4 o;
    o[0] = (__bf16)v.x; o[1] = (__bf16)v.y; o[2] = (__bf16)v.z; o[3] = (__bf16)v.w;
    *(bf16x4*)(xb + 4L * i) = o;
  } else { // g2t partials
    int t = blk - 10624;       // 0..503
    int i = t % 63, c = t / 63;
    int d0 = c * 64, k = tid;
    float a0 = 0.f, a1 = 0.f;
#pragma unroll 8
    for (int u = 0; u < 64; ++u) {
      int d = d0 + u;
      float g = gen[(long)d * 2047 + 992 + i];
      a0 += Wq[(long)d * 512 + k] * g;
      a1 += Wq[(long)d * 512 + k + 256] * g;
    }
    long o = ((long)c * 63 + i) * 512;
    gp[o + k] = a0;
    gp[o + k + 256] = a1;
  }
}

__global__ void g2t_reduce(const float* __restrict__ gp, float* __restrict__ g2t) {
  int idx = blockIdx.x * 256 + threadIdx.x; // 0..32255
  if (idx >= 63 * 512) return;
  float s = 0.f;
#pragma unroll
  for (int c = 0; c < 8; ++c) s += gp[(long)c * 63 * 512 + idx];
  g2t[idx] = s;
}

// ---------------------------------------------------------------------------
// bf16 GEMM, C = A @ B^T. 128x128 tile, BK=32, 4 waves.
// Counted-vmcnt 2-deep pipeline (T4): stage t+1 stays in flight across barriers.
// MODE 1: store bf16 C. MODE 4: f32 C scaled by 1/(aux[row]+1e-8).
// TRIL: A lower-triangular in K -> K-loop ends at m0+128.
template <int MODE, bool TRIL = false>
__global__ __launch_bounds__(256) void gemm_bt(
    const __bf16* __restrict__ A, const __bf16* __restrict__ B, void* __restrict__ Cv,
    const float* __restrict__ aux, int N, int K, long sA, long sB, long sC, int sAux) {
  __shared__ __bf16 As[2][128 * 32];
  __shared__ __bf16 Bs[2][128 * 32];
  const int tid = threadIdx.x;
  const int w = tid >> 6, l = tid & 63;
  const int m0 = blockIdx.y * 128;
  const int n0 = blockIdx.x * 128;
  const int bz = blockIdx.z;
  const __bf16* Ab = A + (long)bz * sA;
  const __bf16* Bb = B + (long)bz * sB;

  const int srow = w * 16 + (l >> 2);
  const int scol = (l & 3) * 8;
  const int wr = (w >> 1) * 64, wc = (w & 1) * 64;
  const int fr = l & 15, fk = (l >> 4) * 8;

  f32x4 acc[4][4] = {};

  const int KM = TRIL ? min(K, m0 + 128) : K;
  const int nt = KM >> 5;

  auto STAGE = [&](int t, int p) {
    const int k0 = t << 5;
    gl_lds16(Ab + (long)(m0 + srow) * K + (k0 + scol),      &As[p][(w * 16) * 32]);
    gl_lds16(Ab + (long)(m0 + 64 + srow) * K + (k0 + scol), &As[p][(64 + w * 16) * 32]);
    gl_lds16(Bb + (long)(n0 + srow) * K + (k0 + scol),      &Bs[p][(w * 16) * 32]);
    gl_lds16(Bb + (long)(n0 + 64 + srow) * K + (k0 + scol), &Bs[p][(64 + w * 16) * 32]);
  };

  STAGE(0, 0);
  STAGE(1, 1);

  for (int t = 0; t < nt; ++t) {
    if (t == nt - 1) asm volatile("s_waitcnt vmcnt(0)\ns_barrier" ::: "memory");
    else             asm volatile("s_waitcnt vmcnt(4)\ns_barrier" ::: "memory");
    const int p = t & 1;
    bf16x8 af[4], bg[4];
#pragma unroll
    for (int i = 0; i < 4; ++i) af[i] = *(const bf16x8*)&As[p][(wr + i * 16 + fr) * 32 + fk];
#pragma unroll
    for (int j = 0; j < 4; ++j) bg[j] = *(const bf16x8*)&Bs[p][(wc + j * 16 + fr) * 32 + fk];
    asm volatile("s_waitcnt lgkmcnt(0)\ns_barrier" ::: "memory");
    if (t + 2 < nt) STAGE(t + 2, p);
#pragma unroll
    for (int i = 0; i < 4; ++i)
#pragma unroll
      for (int j = 0; j < 4; ++j)
        acc[i][j] = __builtin_amdgcn_mfma_f32_16x16x32_bf16(af[i], bg[j], acc[i][j], 0, 0, 0);
  }

  const int rbase = m0 + wr + ((l >> 4) << 2);
  const int cbase = n0 + wc + fr;

  if constexpr (MODE == 1) {
    __bf16* C = (__bf16*)Cv + (long)bz * sC;
#pragma unroll
    for (int i = 0; i < 4; ++i)
#pragma unroll
      for (int r = 0; r < 4; ++r) {
        long row = rbase + i * 16 + r;
#pragma unroll
        for (int j = 0; j < 4; ++j) C[row * N + cbase + j * 16] = (__bf16)acc[i][j][r];
      }
  } else { // MODE 4
    float* C = (float*)Cv + (long)bz * sC;
    const float* ax = aux + (long)bz * sAux;
#pragma unroll
    for (int i = 0; i < 4; ++i)
#pragma unroll
      for (int r = 0; r < 4; ++r) {
        long row = rbase + i * 16 + r;
        float sc = 1.f / (ax[row] + 1e-8f);
#pragma unroll
        for (int j = 0; j < 4; ++j) C[row * N + cbase + j * 16] = acc[i][j][r] * sc;
      }
  }
}

// ---------------------------------------------------------------------------
// Merged x-GEMM, counted-vmcnt 2-deep pipeline. A = xb (16384 x 512).
//   xt in [0,9):  band tile vs Bg  -> gathered S[row][jj], jj = col-1023+(row&1023)
//   xt in [9,13): vT tile vs Pmat -> vT[(row>>10)*512 + col][row&1023]
// XCD-swizzled linear grid: 1664 = 8 * 208 blocks.
__global__ __launch_bounds__(256) void gemm_x(
    const __bf16* __restrict__ A, const __bf16* __restrict__ Bg,
    const __bf16* __restrict__ Pm, __bf16* __restrict__ S, __bf16* __restrict__ vT) {
  __shared__ __bf16 As[2][128 * 32];
  __shared__ __bf16 Bs[2][128 * 32];
  const int tid = threadIdx.x;
  const int w = tid >> 6, l = tid & 63;

  int wgid = blockIdx.x;
  int swz = (wgid & 7) * 208 + (wgid >> 3);
  int y = swz / 13, xt = swz - y * 13;
  const bool band = (xt < 9);
  const int m0 = y * 128;
  const int n0 = band ? (7 - (y & 7) + xt) * 128 : (xt - 9) * 128;
  const __bf16* Bb = band ? Bg : Pm;
  const int K = 512;

  const int srow = w * 16 + (l >> 2);
  const int scol = (l & 3) * 8;
  const int wr = (w >> 1) * 64, wc = (w & 1) * 64;
  const int fr = l & 15, fk = (l >> 4) * 8;

  f32x4 acc[4][4] = {};

  auto STAGE = [&](int t, int p) {
    const int k0 = t << 5;
    gl_lds16(A + (long)(m0 + srow) * K + (k0 + scol),       &As[p][(w * 16) * 32]);
    gl_lds16(A + (long)(m0 + 64 + srow) * K + (k0 + scol),  &As[p][(64 + w * 16) * 32]);
    gl_lds16(Bb + (long)(n0 + srow) * K + (k0 + scol),      &Bs[p][(w * 16) * 32]);
    gl_lds16(Bb + (long)(n0 + 64 + srow) * K + (k0 + scol), &Bs[p][(64 + w * 16) * 32]);
  };

  STAGE(0, 0);
  STAGE(1, 1);

  for (int t = 0; t < 16; ++t) {
    if (t == 15) asm volatile("s_waitcnt vmcnt(0)\ns_barrier" ::: "memory");
    else         asm volatile("s_waitcnt vmcnt(4)\ns_barrier" ::: "memory");
    const int p = t & 1;
    bf16x8 af[4], bg[4];
#pragma unroll
    for (int i = 0; i < 4; ++i) af[i] = *(const bf16x8*)&As[p][(wr + i * 16 + fr) * 32 + fk];
#pragma unroll
    for (int j = 0; j < 4; ++j) bg[j] = *(const bf16x8*)&Bs[p][(wc + j * 16 + fr) * 32 + fk];
    asm volatile("s_waitcnt lgkmcnt(0)\ns_barrier" ::: "memory");
    if (t + 2 < 16) STAGE(t + 2, p);
#pragma unroll
    for (int i = 0; i < 4; ++i)
#pragma unroll
      for (int j = 0; j < 4; ++j)
        acc[i][j] = __builtin_amdgcn_mfma_f32_16x16x32_bf16(af[i], bg[j], acc[i][j], 0, 0, 0);
  }

  const int rbase = m0 + wr + ((l >> 4) << 2);
  const int cbase = n0 + wc + fr;

  if (band) {
#pragma unroll
    for (int i = 0; i < 4; ++i)
#pragma unroll
      for (int r = 0; r < 4; ++r) {
        int row = rbase + i * 16 + r;
        int lloc = row & 1023;
#pragma unroll
        for (int j = 0; j < 4; ++j) {
          int jj = cbase + j * 16 - 1023 + lloc;
          if ((unsigned)jj < 1024u)
            S[(long)row * 1024 + jj] = (__bf16)acc[i][j][r];
        }
      }
  } else {
#pragma unroll
    for (int i = 0; i < 4; ++i) {
      int gm = rbase + i * 16;
      int bt = gm >> 10, lloc = gm & 1023;
#pragma unroll
      for (int j = 0; j < 4; ++j) {
        bf16x4 pk;
        pk[0] = (__bf16)acc[i][j][0]; pk[1] = (__bf16)acc[i][j][1];
        pk[2] = (__bf16)acc[i][j][2]; pk[3] = (__bf16)acc[i][j][3];
        *(bf16x4*)&vT[((long)bt * 512 + cbase + j * 16) * 1024 + lloc] = pk;
      }
    }
  }
}

// ---------------------------------------------------------------------------
// Cumsum over l of S[b,l,j], 64 chunks of 16 rows, bf16x8-vectorized.
// grid (64,16), 128 threads (8 j per thread).
__global__ __launch_bounds__(128) void chunk_sums(const __bf16* __restrict__ S,
                                                  float* __restrict__ csum) {
  int j0 = threadIdx.x * 8;
  int c = blockIdx.x, b = blockIdx.y;
  const __bf16* Sb = S + (long)b * 1024 * 1024;
  float a[8] = {};
  int l0 = c * 16;
  for (int l = l0; l < l0 + 16; ++l) {
    bf16x8 v = *(const bf16x8*)&Sb[(long)l * 1024 + j0];
#pragma unroll
    for (int k = 0; k < 8; ++k) a[k] += (float)v[k];
  }
  long o = ((long)(b * 64 + c) << 10) + j0;
#pragma unroll
  for (int k = 0; k < 8; ++k) csum[o + k] = a[k];
}

// streaming exclusive scan over the 64 chunks per (b,j)
__global__ void scan_kernel(float* __restrict__ csum) {
  int idx = blockIdx.x * 256 + threadIdx.x; // 0..16383
  int b = idx >> 10, j = idx & 1023;
  long base = ((long)b * 64 << 10) + j;
  float s = 0.f;
  for (int c = 0; c < 64; ++c) {
    long o = base + ((long)c << 10);
    float t = csum[o];
    csum[o] = s;
    s += t;
  }
}

// walk chunk with offset, relu+tril, bf16x8 store, fused rowsum atomics
__global__ __launch_bounds__(128) void cumsum_relu(const __bf16* __restrict__ S,
                                                   const float* __restrict__ csum,
                                                   __bf16* __restrict__ wrelu,
                                                   float* __restrict__ rowsum) {
  int j0 = threadIdx.x * 8;
  int c = blockIdx.x, b = blockIdx.y;
  float run[8];
  long co = ((long)(b * 64 + c) << 10) + j0;
#pragma unroll
  for (int k = 0; k < 8; ++k) run[k] = csum[co + k];
  const __bf16* Sb = S + (long)b * 1024 * 1024;
  __bf16* wr = wrelu + (long)b * 1024 * 1024;
  int l0 = c * 16;
  for (int l = l0; l < l0 + 16; ++l) {
    bf16x8 v = *(const bf16x8*)&Sb[(long)l * 1024 + j0];
    bf16x8 o;
    float rs = 0.f;
#pragma unroll
    for (int k = 0; k < 8; ++k) {
      run[k] += (float)v[k];
      float val = (j0 + k <= l) ? fmaxf(run[k], 0.f) : 0.f;
      o[k] = (__bf16)val;
      rs += val;
    }
    *(bf16x8*)&wr[(long)l * 1024 + j0] = o;
#pragma unroll
    for (int off = 32; off; off >>= 1) rs += __shfl_down(rs, off);
    if ((threadIdx.x & 63) == 0 && rs != 0.f) atomicAdd(&rowsum[b * 1024 + l], rs);
  }
}

// ---------------------------------------------------------------------------
// Exact f32 path for rows l<32 (sign-flip hazard region).
__global__ __launch_bounds__(256) void small_dots(
    const float* __restrict__ x, const float* __restrict__ g2t, float* __restrict__ S) {
  int gid = blockIdx.x * 4 + (threadIdx.x >> 6); // 0..16383
  int lane = threadIdx.x & 63;
  int b = gid >> 10, rem = gid & 1023, m = rem >> 5, j = rem & 31;
  const float4* xr = (const float4*)(x + ((long)b * 1024 + m) * 512);
  const float4* gr = (const float4*)(g2t + (long)(31 - m + j) * 512);
  float4 a0 = xr[lane * 2], a1 = xr[lane * 2 + 1];
  float4 c0 = gr[lane * 2], c1 = gr[lane * 2 + 1];
  float s = a0.x * c0.x + a0.y * c0.y + a0.z * c0.z + a0.w * c0.w
          + a1.x * c1.x + a1.y * c1.y + a1.z * c1.z + a1.w * c1.w;
#pragma unroll
  for (int off = 32; off; off >>= 1) s += __shfl_down(s, off);
  if (lane == 0) S[gid] = s;
}

__global__ __launch_bounds__(1024) void small_scan(
    const float* __restrict__ Sg, __bf16* __restrict__ wrelu, float* __restrict__ rowsum) {
  int b = blockIdx.x, tid = threadIdx.x;
  __shared__ float S[32][33];
  int m = tid >> 5, j = tid & 31;
  S[m][j] = Sg[b * 1024 + tid];
  __syncthreads();
  if (tid < 32) {
    float run = 0.f;
    for (int mm = 0; mm < 32; ++mm) { run += S[mm][tid]; S[mm][tid] = run; }
  }
  __syncthreads();
  float v = (j <= m) ? fmaxf(S[m][j], 0.f) : 0.f;
  wrelu[((long)b * 1024 + m) * 1024 + j] = (__bf16)v;
  float rs = v;
#pragma unroll
  for (int off = 16; off; off >>= 1) rs += __shfl_down(rs, off, 32);
  if (j == 0) rowsum[b * 1024 + m] = rs;
}

// ---------------------------------------------------------------------------
extern "C" void kernel_launch(void* const* d_in, const int* in_sizes, int n_in,
                              void* d_out, int out_size, void* d_ws, size_t ws_size,
                              hipStream_t stream) {
  const float* x   = (const float*)d_in[0];
  const float* gen = (const float*)d_in[1];
  const float* Wq  = (const float*)d_in[2];
  const float* Wv  = (const float*)d_in[3];
  const float* Wc  = (const float*)d_in[4];

  char* ws = (char*)d_ws;
  __bf16* xb    = (__bf16*)(ws + 0L);
  __bf16* vT    = (__bf16*)(ws + 33554432L);
  __bf16* Smat  = (__bf16*)(ws + 67108864L);   // gathered scores, 32 MiB
  __bf16* wrelu = (__bf16*)(ws + 134217728L);
  __bf16* genT  = (__bf16*)(ws + 167772160L);
  __bf16* wqT   = (__bf16*)(ws + 169869312L);
  __bf16* wvT   = (__bf16*)(ws + 170393600L);
  __bf16* wcb   = (__bf16*)(ws + 170917888L);
  float*  g2t   = (float*)(ws + 171442176L);
  // overlays in the free region at 16 MiB:
  float*  csum  = (float*)(ws + 16777216L);            // 4 MiB (16*64*1024 f32)
  float*  rsum  = (float*)(ws + 16777216L + 4194304L); // 64 KiB
  float*  Sbuf  = (float*)(ws + 16777216L + 4259840L); // 64 KiB
  // overlays in the free region at 48 MiB:
  __bf16* Pmat  = (__bf16*)(ws + 50331648L);           // 512x512 bf16 (Wc@Wv)
  __bf16* Bg    = (__bf16*)(ws + 51380224L);           // 2048x512 bf16 (gen^T@Wq^T)
  float*  gp    = (float*)(ws + 58720256L);            // 1 MiB g2t partials

  // merged prep: transposes + f2bf (Wc, x) + genT + g2t partials
  prep_kernel<<<11128, 256, 0, stream>>>(x, gen, Wq, Wv, Wc, xb, genT, wqT, wvT, wcb, gp);
  g2t_reduce<<<126, 256, 0, stream>>>(gp, g2t);

  // Weight folding: P = Wc@Wv, Bg = gen^T@Wq^T
  gemm_bt<1><<<dim3(4, 4, 1), 256, 0, stream>>>(wcb, wvT, Pmat, nullptr, 512, 512, 0, 0, 0, 0);
  gemm_bt<1><<<dim3(4, 16, 1), 256, 0, stream>>>(genT, wqT, Bg, nullptr, 512, 512, 0, 0, 0, 0);

  // merged: gathered S = band(x@Bg^T) ; vT = (x@P^T)^T   (XCD-swizzled, counted-vmcnt)
  gemm_x<<<1664, 256, 0, stream>>>(xb, Bg, Pmat, Smat, vT);

  // cumsum + relu/tril + fused rowsum (64 chunks of 16)
  chunk_sums<<<dim3(64, 16), 128, 0, stream>>>(Smat, csum);
  scan_kernel<<<64, 256, 0, stream>>>(csum);
  hipMemsetAsync(rsum, 0, 16 * 1024 * 4, stream);
  cumsum_relu<<<dim3(64, 16), 128, 0, stream>>>(Smat, csum, wrelu, rsum);

  // exact f32 fix for rows l<32
  small_dots<<<4096, 256, 0, stream>>>(x, g2t, Sbuf);
  small_scan<<<16, 1024, 0, stream>>>(Sbuf, wrelu, rsum);

  // OUT = normalize(Wrelu) @ vc  (batched, triangular) -> f32 d_out directly
  gemm_bt<4, true><<<dim3(4, 8, 16), 256, 0, stream>>>(wrelu, vT, d_out, rsum, 512, 1024,
                                                 1024L * 1024, 512L * 1024, 512L * 1024, 1024);
}

// Round 10
// 158.130 us; speedup vs baseline: 1.8461x; 1.0067x over previous
//
#include <hip/hip_runtime.h>
#include <hip/hip_bf16.h>

typedef __attribute__((ext_vector_type(8))) __bf16 bf16x8;
typedef __attribute__((ext_vector_type(4))) __bf16 bf16x4;
typedef __attribute__((ext_vector_type(4))) float  f32x4;

// ---------------------------------------------------------------------------
// async global->LDS, 16B per lane. LDS dest must be wave-uniform base.
__device__ __forceinline__ void gl_lds16(const __bf16* g, __bf16* l) {
  __builtin_amdgcn_global_load_lds(
      (const __attribute__((address_space(1))) void*)g,
      (__attribute__((address_space(3))) void*)l,
      16, 0, 0);
}

// ---------------------------------------------------------------------------
// Merged prep: role-switched by block range.
__global__ __launch_bounds__(256) void prep_kernel(
    const float* __restrict__ x, const float* __restrict__ gen,
    const float* __restrict__ Wq, const float* __restrict__ Wv, const float* __restrict__ Wc,
    __bf16* __restrict__ xb, __bf16* __restrict__ genT,
    __bf16* __restrict__ wqT, __bf16* __restrict__ wvT, __bf16* __restrict__ wcb,
    float* __restrict__ gp) {
  __shared__ float S[64][65];
  const int blk = blockIdx.x, tid = threadIdx.x;

  if (blk < 128) { // transposes
    const float* in = (blk < 64) ? Wq : Wv;
    __bf16* out = (blk < 64) ? wqT : wvT;
    int t = blk & 63;
    int tx = tid & 63, ty = tid >> 6;
    int d0 = (t >> 3) * 64, e0 = (t & 7) * 64;
#pragma unroll
    for (int i = 0; i < 16; ++i) {
      int di = i * 4 + ty;
      S[di][tx] = in[(long)(d0 + di) * 512 + e0 + tx];
    }
    __syncthreads();
#pragma unroll
    for (int i = 0; i < 16; ++i) {
      int ei = i * 4 + ty;
      out[(long)(e0 + ei) * 512 + d0 + tx] = (__bf16)S[tx][ei];
    }
  } else if (blk < 384) { // Wc f2bf
    int i = (blk - 128) * 256 + tid;
    float4 v = ((const float4*)Wc)[i];
    bf16x4 o;
    o[0] = (__bf16)v.x; o[1] = (__bf16)v.y; o[2] = (__bf16)v.z; o[3] = (__bf16)v.w;
    *(bf16x4*)(wcb + 4L * i) = o;
  } else if (blk < 2432) { // genT
    int i = blk - 384;
    for (int d = tid; d < 512; d += 256) {
      float v = (i < 2047) ? gen[(long)d * 2047 + i] : 0.f;
      genT[(long)i * 512 + d] = (__bf16)v;
    }
  } else if (blk < 10624) { // x f2bf
    int i = (blk - 2432) * 256 + tid;
    float4 v = ((const float4*)x)[i];
    bf16x4 o;
    o[0] = (__bf16)v.x; o[1] = (__bf16)v.y; o[2] = (__bf16)v.z; o[3] = (__bf16)v.w;
    *(bf16x4*)(xb + 4L * i) = o;
  } else { // g2t partials
    int t = blk - 10624;       // 0..503
    int i = t % 63, c = t / 63;
    int d0 = c * 64, k = tid;
    float a0 = 0.f, a1 = 0.f;
#pragma unroll 8
    for (int u = 0; u < 64; ++u) {
      int d = d0 + u;
      float g = gen[(long)d * 2047 + 992 + i];
      a0 += Wq[(long)d * 512 + k] * g;
      a1 += Wq[(long)d * 512 + k + 256] * g;
    }
    long o = ((long)c * 63 + i) * 512;
    gp[o + k] = a0;
    gp[o + k + 256] = a1;
  }
}

__global__ void g2t_reduce(const float* __restrict__ gp, float* __restrict__ g2t) {
  int idx = blockIdx.x * 256 + threadIdx.x; // 0..32255
  if (idx >= 63 * 512) return;
  float s = 0.f;
#pragma unroll
  for (int c = 0; c < 8; ++c) s += gp[(long)c * 63 * 512 + idx];
  g2t[idx] = s;
}

// ---------------------------------------------------------------------------
// bf16 GEMM, C = A @ B^T. 128x128 tile, BK=32, 4 waves, counted-vmcnt 2-deep.
// MODE 1: store bf16 C. MODE 4: f32 C scaled by 1/(aux[row]+1e-8).
// TRIL: A lower-triangular in K -> K-loop ends at m0+128.
template <int MODE, bool TRIL = false>
__global__ __launch_bounds__(256) void gemm_bt(
    const __bf16* __restrict__ A, const __bf16* __restrict__ B, void* __restrict__ Cv,
    const float* __restrict__ aux, int N, int K, long sA, long sB, long sC, int sAux) {
  __shared__ __bf16 As[2][128 * 32];
  __shared__ __bf16 Bs[2][128 * 32];
  const int tid = threadIdx.x;
  const int w = tid >> 6, l = tid & 63;
  const int m0 = blockIdx.y * 128;
  const int n0 = blockIdx.x * 128;
  const int bz = blockIdx.z;
  const __bf16* Ab = A + (long)bz * sA;
  const __bf16* Bb = B + (long)bz * sB;

  const int srow = w * 16 + (l >> 2);
  const int scol = (l & 3) * 8;
  const int wr = (w >> 1) * 64, wc = (w & 1) * 64;
  const int fr = l & 15, fk = (l >> 4) * 8;

  f32x4 acc[4][4] = {};

  const int KM = TRIL ? min(K, m0 + 128) : K;
  const int nt = KM >> 5;

  auto STAGE = [&](int t, int p) {
    const int k0 = t << 5;
    gl_lds16(Ab + (long)(m0 + srow) * K + (k0 + scol),      &As[p][(w * 16) * 32]);
    gl_lds16(Ab + (long)(m0 + 64 + srow) * K + (k0 + scol), &As[p][(64 + w * 16) * 32]);
    gl_lds16(Bb + (long)(n0 + srow) * K + (k0 + scol),      &Bs[p][(w * 16) * 32]);
    gl_lds16(Bb + (long)(n0 + 64 + srow) * K + (k0 + scol), &Bs[p][(64 + w * 16) * 32]);
  };

  STAGE(0, 0);
  STAGE(1, 1);

  for (int t = 0; t < nt; ++t) {
    if (t == nt - 1) asm volatile("s_waitcnt vmcnt(0)\ns_barrier" ::: "memory");
    else             asm volatile("s_waitcnt vmcnt(4)\ns_barrier" ::: "memory");
    const int p = t & 1;
    bf16x8 af[4], bg[4];
#pragma unroll
    for (int i = 0; i < 4; ++i) af[i] = *(const bf16x8*)&As[p][(wr + i * 16 + fr) * 32 + fk];
#pragma unroll
    for (int j = 0; j < 4; ++j) bg[j] = *(const bf16x8*)&Bs[p][(wc + j * 16 + fr) * 32 + fk];
    asm volatile("s_waitcnt lgkmcnt(0)\ns_barrier" ::: "memory");
    if (t + 2 < nt) STAGE(t + 2, p);
#pragma unroll
    for (int i = 0; i < 4; ++i)
#pragma unroll
      for (int j = 0; j < 4; ++j)
        acc[i][j] = __builtin_amdgcn_mfma_f32_16x16x32_bf16(af[i], bg[j], acc[i][j], 0, 0, 0);
  }

  const int rbase = m0 + wr + ((l >> 4) << 2);
  const int cbase = n0 + wc + fr;

  if constexpr (MODE == 1) {
    __bf16* C = (__bf16*)Cv + (long)bz * sC;
#pragma unroll
    for (int i = 0; i < 4; ++i)
#pragma unroll
      for (int r = 0; r < 4; ++r) {
        long row = rbase + i * 16 + r;
#pragma unroll
        for (int j = 0; j < 4; ++j) C[row * N + cbase + j * 16] = (__bf16)acc[i][j][r];
      }
  } else { // MODE 4
    float* C = (float*)Cv + (long)bz * sC;
    const float* ax = aux + (long)bz * sAux;
#pragma unroll
    for (int i = 0; i < 4; ++i)
#pragma unroll
      for (int r = 0; r < 4; ++r) {
        long row = rbase + i * 16 + r;
        float sc = 1.f / (ax[row] + 1e-8f);
#pragma unroll
        for (int j = 0; j < 4; ++j) C[row * N + cbase + j * 16] = acc[i][j][r] * sc;
      }
  }
}

// ---------------------------------------------------------------------------
// Merged x-GEMM, BM=256 x BN=128, 512 threads / 8 waves (4M x 2N), BK=32,
// counted-vmcnt 2-deep (3 loads/stage -> vmcnt(3)). A = xb (16384 x 512).
// Per m-tile y (256 rows, l0 = m0&1023): 14 n-tiles:
//   xt in [0,10):  band vs Bg, n0 = (6 - 2*(y&3) + xt)*128
//                  -> gathered S[row][jj], jj = col-1023+(row&1023)
//   xt in [10,14): vT vs Pmat, n0 = (xt-10)*128
//                  -> vT[(row>>10)*512 + col][row&1023]
// XCD-swizzled linear grid: 896 = 8 * 112 blocks.
__global__ __launch_bounds__(512) void gemm_x(
    const __bf16* __restrict__ A, const __bf16* __restrict__ Bg,
    const __bf16* __restrict__ Pm, __bf16* __restrict__ S, __bf16* __restrict__ vT) {
  __shared__ __bf16 As[2][256 * 32];
  __shared__ __bf16 Bs[2][128 * 32];
  const int tid = threadIdx.x;
  const int w = tid >> 6, l = tid & 63;

  int wgid = blockIdx.x;
  int swz = (wgid & 7) * 112 + (wgid >> 3);
  int y = swz / 14, xt = swz - y * 14;
  const bool band = (xt < 10);
  const int m0 = y * 256;
  const int n0 = band ? (6 - 2 * (y & 3) + xt) * 128 : (xt - 10) * 128;
  const __bf16* Bb = band ? Bg : Pm;
  const int K = 512;

  const int srow = w * 16 + (l >> 2);   // 8 waves x 16 rows = 128 rows per call
  const int scol = (l & 3) * 8;
  const int wr = (w >> 1) * 64;         // 4 M-groups of 64
  const int wc = (w & 1) * 64;          // 2 N-groups of 64
  const int fr = l & 15, fk = (l >> 4) * 8;

  f32x4 acc[4][4] = {};

  auto STAGE = [&](int t, int p) {
    const int k0 = t << 5;
    gl_lds16(A + (long)(m0 + srow) * K + (k0 + scol),        &As[p][(w * 16) * 32]);
    gl_lds16(A + (long)(m0 + 128 + srow) * K + (k0 + scol),  &As[p][(128 + w * 16) * 32]);
    gl_lds16(Bb + (long)(n0 + srow) * K + (k0 + scol),       &Bs[p][(w * 16) * 32]);
  };

  STAGE(0, 0);
  STAGE(1, 1);

  for (int t = 0; t < 16; ++t) {
    if (t == 15) asm volatile("s_waitcnt vmcnt(0)\ns_barrier" ::: "memory");
    else         asm volatile("s_waitcnt vmcnt(3)\ns_barrier" ::: "memory");
    const int p = t & 1;
    bf16x8 af[4], bg[4];
#pragma unroll
    for (int i = 0; i < 4; ++i) af[i] = *(const bf16x8*)&As[p][(wr + i * 16 + fr) * 32 + fk];
#pragma unroll
    for (int j = 0; j < 4; ++j) bg[j] = *(const bf16x8*)&Bs[p][(wc + j * 16 + fr) * 32 + fk];
    asm volatile("s_waitcnt lgkmcnt(0)\ns_barrier" ::: "memory");
    if (t + 2 < 16) STAGE(t + 2, p);
#pragma unroll
    for (int i = 0; i < 4; ++i)
#pragma unroll
      for (int j = 0; j < 4; ++j)
        acc[i][j] = __builtin_amdgcn_mfma_f32_16x16x32_bf16(af[i], bg[j], acc[i][j], 0, 0, 0);
  }

  const int rbase = m0 + wr + ((l >> 4) << 2);
  const int cbase = n0 + wc + fr;

  if (band) {
#pragma unroll
    for (int i = 0; i < 4; ++i)
#pragma unroll
      for (int r = 0; r < 4; ++r) {
        int row = rbase + i * 16 + r;
        int lloc = row & 1023;
#pragma unroll
        for (int j = 0; j < 4; ++j) {
          int jj = cbase + j * 16 - 1023 + lloc;
          if ((unsigned)jj < 1024u)
            S[(long)row * 1024 + jj] = (__bf16)acc[i][j][r];
        }
      }
  } else {
#pragma unroll
    for (int i = 0; i < 4; ++i) {
      int gm = rbase + i * 16;
      int bt = gm >> 10, lloc = gm & 1023;
#pragma unroll
      for (int j = 0; j < 4; ++j) {
        bf16x4 pk;
        pk[0] = (__bf16)acc[i][j][0]; pk[1] = (__bf16)acc[i][j][1];
        pk[2] = (__bf16)acc[i][j][2]; pk[3] = (__bf16)acc[i][j][3];
        *(bf16x4*)&vT[((long)bt * 512 + cbase + j * 16) * 1024 + lloc] = pk;
      }
    }
  }
}

// ---------------------------------------------------------------------------
// Cumsum over l of S[b,l,j], 64 chunks of 16 rows, bf16x8-vectorized.
__global__ __launch_bounds__(128) void chunk_sums(const __bf16* __restrict__ S,
                                                  float* __restrict__ csum) {
  int j0 = threadIdx.x * 8;
  int c = blockIdx.x, b = blockIdx.y;
  const __bf16* Sb = S + (long)b * 1024 * 1024;
  float a[8] = {};
  int l0 = c * 16;
  for (int l = l0; l < l0 + 16; ++l) {
    bf16x8 v = *(const bf16x8*)&Sb[(long)l * 1024 + j0];
#pragma unroll
    for (int k = 0; k < 8; ++k) a[k] += (float)v[k];
  }
  long o = ((long)(b * 64 + c) << 10) + j0;
#pragma unroll
  for (int k = 0; k < 8; ++k) csum[o + k] = a[k];
}

// streaming exclusive scan over the 64 chunks per (b,j)
__global__ void scan_kernel(float* __restrict__ csum) {
  int idx = blockIdx.x * 256 + threadIdx.x; // 0..16383
  int b = idx >> 10, j = idx & 1023;
  long base = ((long)b * 64 << 10) + j;
  float s = 0.f;
  for (int c = 0; c < 64; ++c) {
    long o = base + ((long)c << 10);
    float t = csum[o];
    csum[o] = s;
    s += t;
  }
}

// walk chunk with offset, relu+tril, bf16x8 store, fused rowsum atomics
__global__ __launch_bounds__(128) void cumsum_relu(const __bf16* __restrict__ S,
                                                   const float* __restrict__ csum,
                                                   __bf16* __restrict__ wrelu,
                                                   float* __restrict__ rowsum) {
  int j0 = threadIdx.x * 8;
  int c = blockIdx.x, b = blockIdx.y;
  float run[8];
  long co = ((long)(b * 64 + c) << 10) + j0;
#pragma unroll
  for (int k = 0; k < 8; ++k) run[k] = csum[co + k];
  const __bf16* Sb = S + (long)b * 1024 * 1024;
  __bf16* wr = wrelu + (long)b * 1024 * 1024;
  int l0 = c * 16;
  for (int l = l0; l < l0 + 16; ++l) {
    bf16x8 v = *(const bf16x8*)&Sb[(long)l * 1024 + j0];
    bf16x8 o;
    float rs = 0.f;
#pragma unroll
    for (int k = 0; k < 8; ++k) {
      run[k] += (float)v[k];
      float val = (j0 + k <= l) ? fmaxf(run[k], 0.f) : 0.f;
      o[k] = (__bf16)val;
      rs += val;
    }
    *(bf16x8*)&wr[(long)l * 1024 + j0] = o;
#pragma unroll
    for (int off = 32; off; off >>= 1) rs += __shfl_down(rs, off);
    if ((threadIdx.x & 63) == 0 && rs != 0.f) atomicAdd(&rowsum[b * 1024 + l], rs);
  }
}

// ---------------------------------------------------------------------------
// Exact f32 path for rows l<32 (sign-flip hazard region).
__global__ __launch_bounds__(256) void small_dots(
    const float* __restrict__ x, const float* __restrict__ g2t, float* __restrict__ S) {
  int gid = blockIdx.x * 4 + (threadIdx.x >> 6); // 0..16383
  int lane = threadIdx.x & 63;
  int b = gid >> 10, rem = gid & 1023, m = rem >> 5, j = rem & 31;
  const float4* xr = (const float4*)(x + ((long)b * 1024 + m) * 512);
  const float4* gr = (const float4*)(g2t + (long)(31 - m + j) * 512);
  float4 a0 = xr[lane * 2], a1 = xr[lane * 2 + 1];
  float4 c0 = gr[lane * 2], c1 = gr[lane * 2 + 1];
  float s = a0.x * c0.x + a0.y * c0.y + a0.z * c0.z + a0.w * c0.w
          + a1.x * c1.x + a1.y * c1.y + a1.z * c1.z + a1.w * c1.w;
#pragma unroll
  for (int off = 32; off; off >>= 1) s += __shfl_down(s, off);
  if (lane == 0) S[gid] = s;
}

__global__ __launch_bounds__(1024) void small_scan(
    const float* __restrict__ Sg, __bf16* __restrict__ wrelu, float* __restrict__ rowsum) {
  int b = blockIdx.x, tid = threadIdx.x;
  __shared__ float S[32][33];
  int m = tid >> 5, j = tid & 31;
  S[m][j] = Sg[b * 1024 + tid];
  __syncthreads();
  if (tid < 32) {
    float run = 0.f;
    for (int mm = 0; mm < 32; ++mm) { run += S[mm][tid]; S[mm][tid] = run; }
  }
  __syncthreads();
  float v = (j <= m) ? fmaxf(S[m][j], 0.f) : 0.f;
  wrelu[((long)b * 1024 + m) * 1024 + j] = (__bf16)v;
  float rs = v;
#pragma unroll
  for (int off = 16; off; off >>= 1) rs += __shfl_down(rs, off, 32);
  if (j == 0) rowsum[b * 1024 + m] = rs;
}

// ---------------------------------------------------------------------------
extern "C" void kernel_launch(void* const* d_in, const int* in_sizes, int n_in,
                              void* d_out, int out_size, void* d_ws, size_t ws_size,
                              hipStream_t stream) {
  const float* x   = (const float*)d_in[0];
  const float* gen = (const float*)d_in[1];
  const float* Wq  = (const float*)d_in[2];
  const float* Wv  = (const float*)d_in[3];
  const float* Wc  = (const float*)d_in[4];

  char* ws = (char*)d_ws;
  __bf16* xb    = (__bf16*)(ws + 0L);
  __bf16* vT    = (__bf16*)(ws + 33554432L);
  __bf16* Smat  = (__bf16*)(ws + 67108864L);   // gathered scores, 32 MiB
  __bf16* wrelu = (__bf16*)(ws + 134217728L);
  __bf16* genT  = (__bf16*)(ws + 167772160L);
  __bf16* wqT   = (__bf16*)(ws + 169869312L);
  __bf16* wvT   = (__bf16*)(ws + 170393600L);
  __bf16* wcb   = (__bf16*)(ws + 170917888L);
  float*  g2t   = (float*)(ws + 171442176L);
  // overlays in the free region at 16 MiB:
  float*  csum  = (float*)(ws + 16777216L);            // 4 MiB (16*64*1024 f32)
  float*  rsum  = (float*)(ws + 16777216L + 4194304L); // 64 KiB
  float*  Sbuf  = (float*)(ws + 16777216L + 4259840L); // 64 KiB
  // overlays in the free region at 48 MiB:
  __bf16* Pmat  = (__bf16*)(ws + 50331648L);           // 512x512 bf16 (Wc@Wv)
  __bf16* Bg    = (__bf16*)(ws + 51380224L);           // 2048x512 bf16 (gen^T@Wq^T)
  float*  gp    = (float*)(ws + 58720256L);            // 1 MiB g2t partials

  // merged prep: transposes + f2bf (Wc, x) + genT + g2t partials
  prep_kernel<<<11128, 256, 0, stream>>>(x, gen, Wq, Wv, Wc, xb, genT, wqT, wvT, wcb, gp);
  g2t_reduce<<<126, 256, 0, stream>>>(gp, g2t);

  // Weight folding: P = Wc@Wv, Bg = gen^T@Wq^T
  gemm_bt<1><<<dim3(4, 4, 1), 256, 0, stream>>>(wcb, wvT, Pmat, nullptr, 512, 512, 0, 0, 0, 0);
  gemm_bt<1><<<dim3(4, 16, 1), 256, 0, stream>>>(genT, wqT, Bg, nullptr, 512, 512, 0, 0, 0, 0);

  // merged: gathered S = band(x@Bg^T) ; vT = (x@P^T)^T   (256x128 tile, XCD swizzle)
  gemm_x<<<896, 512, 0, stream>>>(xb, Bg, Pmat, Smat, vT);

  // cumsum + relu/tril + fused rowsum (64 chunks of 16)
  chunk_sums<<<dim3(64, 16), 128, 0, stream>>>(Smat, csum);
  scan_kernel<<<64, 256, 0, stream>>>(csum);
  hipMemsetAsync(rsum, 0, 16 * 1024 * 4, stream);
  cumsum_relu<<<dim3(64, 16), 128, 0, stream>>>(Smat, csum, wrelu, rsum);

  // exact f32 fix for rows l<32
  small_dots<<<4096, 256, 0, stream>>>(x, g2t, Sbuf);
  small_scan<<<16, 1024, 0, stream>>>(Sbuf, wrelu, rsum);

  // OUT = normalize(Wrelu) @ vc  (batched, triangular) -> f32 d_out directly
  gemm_bt<4, true><<<dim3(4, 8, 16), 256, 0, stream>>>(wrelu, vT, d_out, rsum, 512, 1024,
                                                 1024L * 1024, 512L * 1024, 512L * 1024, 1024);
}

// Round 11
// 143.892 us; speedup vs baseline: 2.0287x; 1.0989x over previous
//
#include <hip/hip_runtime.h>
#include <hip/hip_bf16.h>

typedef __attribute__((ext_vector_type(8))) __bf16 bf16x8;
typedef __attribute__((ext_vector_type(4))) __bf16 bf16x4;
typedef __attribute__((ext_vector_type(4))) float  f32x4;

// ---------------------------------------------------------------------------
// async global->LDS, 16B per lane. LDS dest must be wave-uniform base.
__device__ __forceinline__ void gl_lds16(const __bf16* g, __bf16* l) {
  __builtin_amdgcn_global_load_lds(
      (const __attribute__((address_space(1))) void*)g,
      (__attribute__((address_space(3))) void*)l,
      16, 0, 0);
}

// ---------------------------------------------------------------------------
// Merged prep: role-switched by block range.
__global__ __launch_bounds__(256) void prep_kernel(
    const float* __restrict__ x, const float* __restrict__ gen,
    const float* __restrict__ Wq, const float* __restrict__ Wv, const float* __restrict__ Wc,
    __bf16* __restrict__ xb, __bf16* __restrict__ genT,
    __bf16* __restrict__ wqT, __bf16* __restrict__ wvT, __bf16* __restrict__ wcb,
    float* __restrict__ gp) {
  __shared__ float S[64][65];
  const int blk = blockIdx.x, tid = threadIdx.x;

  if (blk < 128) { // transposes
    const float* in = (blk < 64) ? Wq : Wv;
    __bf16* out = (blk < 64) ? wqT : wvT;
    int t = blk & 63;
    int tx = tid & 63, ty = tid >> 6;
    int d0 = (t >> 3) * 64, e0 = (t & 7) * 64;
#pragma unroll
    for (int i = 0; i < 16; ++i) {
      int di = i * 4 + ty;
      S[di][tx] = in[(long)(d0 + di) * 512 + e0 + tx];
    }
    __syncthreads();
#pragma unroll
    for (int i = 0; i < 16; ++i) {
      int ei = i * 4 + ty;
      out[(long)(e0 + ei) * 512 + d0 + tx] = (__bf16)S[tx][ei];
    }
  } else if (blk < 384) { // Wc f2bf
    int i = (blk - 128) * 256 + tid;
    float4 v = ((const float4*)Wc)[i];
    bf16x4 o;
    o[0] = (__bf16)v.x; o[1] = (__bf16)v.y; o[2] = (__bf16)v.z; o[3] = (__bf16)v.w;
    *(bf16x4*)(wcb + 4L * i) = o;
  } else if (blk < 2432) { // genT
    int i = blk - 384;
    for (int d = tid; d < 512; d += 256) {
      float v = (i < 2047) ? gen[(long)d * 2047 + i] : 0.f;
      genT[(long)i * 512 + d] = (__bf16)v;
    }
  } else if (blk < 10624) { // x f2bf
    int i = (blk - 2432) * 256 + tid;
    float4 v = ((const float4*)x)[i];
    bf16x4 o;
    o[0] = (__bf16)v.x; o[1] = (__bf16)v.y; o[2] = (__bf16)v.z; o[3] = (__bf16)v.w;
    *(bf16x4*)(xb + 4L * i) = o;
  } else { // g2t partials
    int t = blk - 10624;       // 0..503
    int i = t % 63, c = t / 63;
    int d0 = c * 64, k = tid;
    float a0 = 0.f, a1 = 0.f;
#pragma unroll 8
    for (int u = 0; u < 64; ++u) {
      int d = d0 + u;
      float g = gen[(long)d * 2047 + 992 + i];
      a0 += Wq[(long)d * 512 + k] * g;
      a1 += Wq[(long)d * 512 + k + 256] * g;
    }
    long o = ((long)c * 63 + i) * 512;
    gp[o + k] = a0;
    gp[o + k + 256] = a1;
  }
}

__global__ void g2t_reduce(const float* __restrict__ gp, float* __restrict__ g2t) {
  int idx = blockIdx.x * 256 + threadIdx.x; // 0..32255
  if (idx >= 63 * 512) return;
  float s = 0.f;
#pragma unroll
  for (int c = 0; c < 8; ++c) s += gp[(long)c * 63 * 512 + idx];
  g2t[idx] = s;
}

// ---------------------------------------------------------------------------
// Shared 128x128 3-deep counted-vmcnt GEMM core (BK=32, 4 waves, C=A@B^T).
// 4 loads/stage -> steady wait vmcnt(8), tail 4/0.
__device__ __forceinline__ void gemm128_body(
    const __bf16* __restrict__ Ab, const __bf16* __restrict__ Bb,
    __bf16 (*As)[128 * 32], __bf16 (*Bs)[128 * 32],
    int m0, int n0, int K, int nt, f32x4 (&acc)[4][4]) {
  const int tid = threadIdx.x;
  const int w = tid >> 6, l = tid & 63;
  const int srow = w * 16 + (l >> 2), scol = (l & 3) * 8;
  const int wr = (w >> 1) * 64, wc = (w & 1) * 64;
  const int fr = l & 15, fk = (l >> 4) * 8;

  auto STAGE = [&](int t, int p) {
    const int k0 = t << 5;
    gl_lds16(Ab + (long)(m0 + srow) * K + (k0 + scol),      &As[p][(w * 16) * 32]);
    gl_lds16(Ab + (long)(m0 + 64 + srow) * K + (k0 + scol), &As[p][(64 + w * 16) * 32]);
    gl_lds16(Bb + (long)(n0 + srow) * K + (k0 + scol),      &Bs[p][(w * 16) * 32]);
    gl_lds16(Bb + (long)(n0 + 64 + srow) * K + (k0 + scol), &Bs[p][(64 + w * 16) * 32]);
  };
  STAGE(0, 0);
  if (nt > 1) STAGE(1, 1);
  if (nt > 2) STAGE(2, 2);
  int p = 0;
  for (int t = 0; t < nt; ++t) {
    const int ahead = nt - 1 - t;
    if (ahead >= 2)      asm volatile("s_waitcnt vmcnt(8)\ns_barrier" ::: "memory");
    else if (ahead == 1) asm volatile("s_waitcnt vmcnt(4)\ns_barrier" ::: "memory");
    else                 asm volatile("s_waitcnt vmcnt(0)\ns_barrier" ::: "memory");
    bf16x8 af[4], bg[4];
#pragma unroll
    for (int i = 0; i < 4; ++i) af[i] = *(const bf16x8*)&As[p][(wr + i * 16 + fr) * 32 + fk];
#pragma unroll
    for (int j = 0; j < 4; ++j) bg[j] = *(const bf16x8*)&Bs[p][(wc + j * 16 + fr) * 32 + fk];
    asm volatile("s_waitcnt lgkmcnt(0)\ns_barrier" ::: "memory");
    if (t + 3 < nt) STAGE(t + 3, p);
#pragma unroll
    for (int i = 0; i < 4; ++i)
#pragma unroll
      for (int j = 0; j < 4; ++j)
        acc[i][j] = __builtin_amdgcn_mfma_f32_16x16x32_bf16(af[i], bg[j], acc[i][j], 0, 0, 0);
    p = (p == 2) ? 0 : p + 1;
  }
}

// ---------------------------------------------------------------------------
// Merged weight-folding GEMMs in one dispatch (80 blocks):
//   blk [0,16):  Pmat = wcb @ wvT^T   (512x512, grid 4x4)
//   blk [16,80): Bg   = genT @ wqT^T  (2048x512, grid 16x4)
__global__ __launch_bounds__(256) void gemm_fold(
    const __bf16* __restrict__ A1, const __bf16* __restrict__ B1, __bf16* __restrict__ C1,
    const __bf16* __restrict__ A2, const __bf16* __restrict__ B2, __bf16* __restrict__ C2) {
  __shared__ __bf16 As[3][128 * 32];
  __shared__ __bf16 Bs[3][128 * 32];
  const int b = blockIdx.x;
  const __bf16 *Ab, *Bb; __bf16* C; int m0, n0;
  if (b < 16) { Ab = A1; Bb = B1; C = C1; m0 = (b >> 2) * 128; n0 = (b & 3) * 128; }
  else { int t = b - 16; Ab = A2; Bb = B2; C = C2; m0 = (t >> 2) * 128; n0 = (t & 3) * 128; }

  f32x4 acc[4][4] = {};
  gemm128_body(Ab, Bb, As, Bs, m0, n0, 512, 16, acc);

  const int l = threadIdx.x & 63, w = threadIdx.x >> 6;
  const int rbase = m0 + (w >> 1) * 64 + ((l >> 4) << 2);
  const int cbase = n0 + (w & 1) * 64 + (l & 15);
#pragma unroll
  for (int i = 0; i < 4; ++i)
#pragma unroll
    for (int r = 0; r < 4; ++r) {
      long row = rbase + i * 16 + r;
#pragma unroll
      for (int j = 0; j < 4; ++j) C[row * 512 + cbase + j * 16] = (__bf16)acc[i][j][r];
    }
}

// ---------------------------------------------------------------------------
// Final GEMM: OUT[b] = normalize(Wrelu[b]) @ vT[b]^T -> f32 d_out.
// TRIL: K-loop ends at m0+128. 3-deep core.
__global__ __launch_bounds__(256) void gemm_out(
    const __bf16* __restrict__ A, const __bf16* __restrict__ B, float* __restrict__ Cv,
    const float* __restrict__ aux) {
  __shared__ __bf16 As[3][128 * 32];
  __shared__ __bf16 Bs[3][128 * 32];
  const int m0 = blockIdx.y * 128, n0 = blockIdx.x * 128, bz = blockIdx.z;
  const int K = 1024;
  const __bf16* Ab = A + (long)bz * 1024 * 1024;
  const __bf16* Bb = B + (long)bz * 512 * 1024;
  const int nt = (m0 + 128) >> 5;   // min(K, m0+128)/32, m0+128 <= 1024

  f32x4 acc[4][4] = {};
  gemm128_body(Ab, Bb, As, Bs, m0, n0, K, nt, acc);

  const int l = threadIdx.x & 63, w = threadIdx.x >> 6;
  const int rbase = m0 + (w >> 1) * 64 + ((l >> 4) << 2);
  const int cbase = n0 + (w & 1) * 64 + (l & 15);
  float* C = Cv + (long)bz * 512 * 1024;
  const float* ax = aux + bz * 1024;
#pragma unroll
  for (int i = 0; i < 4; ++i)
#pragma unroll
    for (int r = 0; r < 4; ++r) {
      long row = rbase + i * 16 + r;
      float sc = 1.f / (ax[row] + 1e-8f);
#pragma unroll
      for (int j = 0; j < 4; ++j) C[row * 512 + cbase + j * 16] = acc[i][j][r] * sc;
    }
}

// ---------------------------------------------------------------------------
// Merged x-GEMM, BM=256 x BN=128, 512 threads / 8 waves, BK=32, 3-deep
// counted-vmcnt (3 loads/stage -> steady vmcnt(6)). A = xb (16384 x 512).
// Per m-tile y (256 rows): 14 n-tiles:
//   xt in [0,10):  band vs Bg, n0 = (6 - 2*(y&3) + xt)*128
//                  -> gathered S[row][jj], jj = col-1023+(row&1023)
//   xt in [10,14): vT vs Pmat -> vT[(row>>10)*512 + col][row&1023]
// XCD-swizzled linear grid: 896 = 8 * 112 blocks.
__global__ __launch_bounds__(512) void gemm_x(
    const __bf16* __restrict__ A, const __bf16* __restrict__ Bg,
    const __bf16* __restrict__ Pm, __bf16* __restrict__ S, __bf16* __restrict__ vT) {
  __shared__ __bf16 As[3][256 * 32];
  __shared__ __bf16 Bs[3][128 * 32];
  const int tid = threadIdx.x;
  const int w = tid >> 6, l = tid & 63;

  int wgid = blockIdx.x;
  int swz = (wgid & 7) * 112 + (wgid >> 3);
  int y = swz / 14, xt = swz - y * 14;
  const bool band = (xt < 10);
  const int m0 = y * 256;
  const int n0 = band ? (6 - 2 * (y & 3) + xt) * 128 : (xt - 10) * 128;
  const __bf16* Bb = band ? Bg : Pm;
  const int K = 512;

  const int srow = w * 16 + (l >> 2);
  const int scol = (l & 3) * 8;
  const int wr = (w >> 1) * 64;
  const int wc = (w & 1) * 64;
  const int fr = l & 15, fk = (l >> 4) * 8;

  f32x4 acc[4][4] = {};

  auto STAGE = [&](int t, int p) {
    const int k0 = t << 5;
    gl_lds16(A + (long)(m0 + srow) * K + (k0 + scol),        &As[p][(w * 16) * 32]);
    gl_lds16(A + (long)(m0 + 128 + srow) * K + (k0 + scol),  &As[p][(128 + w * 16) * 32]);
    gl_lds16(Bb + (long)(n0 + srow) * K + (k0 + scol),       &Bs[p][(w * 16) * 32]);
  };

  STAGE(0, 0);
  STAGE(1, 1);
  STAGE(2, 2);

  int p = 0;
  for (int t = 0; t < 16; ++t) {
    const int ahead = 15 - t;
    if (ahead >= 2)      asm volatile("s_waitcnt vmcnt(6)\ns_barrier" ::: "memory");
    else if (ahead == 1) asm volatile("s_waitcnt vmcnt(3)\ns_barrier" ::: "memory");
    else                 asm volatile("s_waitcnt vmcnt(0)\ns_barrier" ::: "memory");
    bf16x8 af[4], bg[4];
#pragma unroll
    for (int i = 0; i < 4; ++i) af[i] = *(const bf16x8*)&As[p][(wr + i * 16 + fr) * 32 + fk];
#pragma unroll
    for (int j = 0; j < 4; ++j) bg[j] = *(const bf16x8*)&Bs[p][(wc + j * 16 + fr) * 32 + fk];
    asm volatile("s_waitcnt lgkmcnt(0)\ns_barrier" ::: "memory");
    if (t + 3 < 16) STAGE(t + 3, p);
#pragma unroll
    for (int i = 0; i < 4; ++i)
#pragma unroll
      for (int j = 0; j < 4; ++j)
        acc[i][j] = __builtin_amdgcn_mfma_f32_16x16x32_bf16(af[i], bg[j], acc[i][j], 0, 0, 0);
    p = (p == 2) ? 0 : p + 1;
  }

  const int rbase = m0 + wr + ((l >> 4) << 2);
  const int cbase = n0 + wc + fr;

  if (band) {
#pragma unroll
    for (int i = 0; i < 4; ++i)
#pragma unroll
      for (int r = 0; r < 4; ++r) {
        int row = rbase + i * 16 + r;
        int lloc = row & 1023;
#pragma unroll
        for (int j = 0; j < 4; ++j) {
          int jj = cbase + j * 16 - 1023 + lloc;
          if ((unsigned)jj < 1024u)
            S[(long)row * 1024 + jj] = (__bf16)acc[i][j][r];
        }
      }
  } else {
#pragma unroll
    for (int i = 0; i < 4; ++i) {
      int gm = rbase + i * 16;
      int bt = gm >> 10, lloc = gm & 1023;
#pragma unroll
      for (int j = 0; j < 4; ++j) {
        bf16x4 pk;
        pk[0] = (__bf16)acc[i][j][0]; pk[1] = (__bf16)acc[i][j][1];
        pk[2] = (__bf16)acc[i][j][2]; pk[3] = (__bf16)acc[i][j][3];
        *(bf16x4*)&vT[((long)bt * 512 + cbase + j * 16) * 1024 + lloc] = pk;
      }
    }
  }
}

// ---------------------------------------------------------------------------
// Cumsum over l of S[b,l,j], 64 chunks of 16 rows, bf16x8-vectorized.
// Blocks with c<8 also zero the rowsum segment (replaces the memset dispatch).
__global__ __launch_bounds__(128) void chunk_sums(const __bf16* __restrict__ S,
                                                  float* __restrict__ csum,
                                                  float* __restrict__ rowsum) {
  int j0 = threadIdx.x * 8;
  int c = blockIdx.x, b = blockIdx.y;
  if (c < 8) rowsum[b * 1024 + c * 128 + threadIdx.x] = 0.f;
  const __bf16* Sb = S + (long)b * 1024 * 1024;
  float a[8] = {};
  int l0 = c * 16;
  for (int l = l0; l < l0 + 16; ++l) {
    bf16x8 v = *(const bf16x8*)&Sb[(long)l * 1024 + j0];
#pragma unroll
    for (int k = 0; k < 8; ++k) a[k] += (float)v[k];
  }
  long o = ((long)(b * 64 + c) << 10) + j0;
#pragma unroll
  for (int k = 0; k < 8; ++k) csum[o + k] = a[k];
}

// streaming exclusive scan over the 64 chunks per (b,j)
__global__ void scan_kernel(float* __restrict__ csum) {
  int idx = blockIdx.x * 256 + threadIdx.x; // 0..16383
  int b = idx >> 10, j = idx & 1023;
  long base = ((long)b * 64 << 10) + j;
  float s = 0.f;
  for (int c = 0; c < 64; ++c) {
    long o = base + ((long)c << 10);
    float t = csum[o];
    csum[o] = s;
    s += t;
  }
}

// walk chunk with offset, relu+tril, bf16x8 store (skip tiles the TRIL GEMM
// never reads: only store when j0 < ceil128(l+1)), fused rowsum atomics
__global__ __launch_bounds__(128) void cumsum_relu(const __bf16* __restrict__ S,
                                                   const float* __restrict__ csum,
                                                   __bf16* __restrict__ wrelu,
                                                   float* __restrict__ rowsum) {
  int j0 = threadIdx.x * 8;
  int c = blockIdx.x, b = blockIdx.y;
  float run[8];
  long co = ((long)(b * 64 + c) << 10) + j0;
#pragma unroll
  for (int k = 0; k < 8; ++k) run[k] = csum[co + k];
  const __bf16* Sb = S + (long)b * 1024 * 1024;
  __bf16* wr = wrelu + (long)b * 1024 * 1024;
  int l0 = c * 16;
  for (int l = l0; l < l0 + 16; ++l) {
    bf16x8 v = *(const bf16x8*)&Sb[(long)l * 1024 + j0];
    bf16x8 o;
    float rs = 0.f;
#pragma unroll
    for (int k = 0; k < 8; ++k) {
      run[k] += (float)v[k];
      float val = (j0 + k <= l) ? fmaxf(run[k], 0.f) : 0.f;
      o[k] = (__bf16)val;
      rs += val;
    }
    if (j0 < (((l >> 7) + 1) << 7))
      *(bf16x8*)&wr[(long)l * 1024 + j0] = o;
#pragma unroll
    for (int off = 32; off; off >>= 1) rs += __shfl_down(rs, off);
    if ((threadIdx.x & 63) == 0 && rs != 0.f) atomicAdd(&rowsum[b * 1024 + l], rs);
  }
}

// ---------------------------------------------------------------------------
// Exact f32 path for rows l<32 (sign-flip hazard region).
__global__ __launch_bounds__(256) void small_dots(
    const float* __restrict__ x, const float* __restrict__ g2t, float* __restrict__ S) {
  int gid = blockIdx.x * 4 + (threadIdx.x >> 6); // 0..16383
  int lane = threadIdx.x & 63;
  int b = gid >> 10, rem = gid & 1023, m = rem >> 5, j = rem & 31;
  const float4* xr = (const float4*)(x + ((long)b * 1024 + m) * 512);
  const float4* gr = (const float4*)(g2t + (long)(31 - m + j) * 512);
  float4 a0 = xr[lane * 2], a1 = xr[lane * 2 + 1];
  float4 c0 = gr[lane * 2], c1 = gr[lane * 2 + 1];
  float s = a0.x * c0.x + a0.y * c0.y + a0.z * c0.z + a0.w * c0.w
          + a1.x * c1.x + a1.y * c1.y + a1.z * c1.z + a1.w * c1.w;
#pragma unroll
  for (int off = 32; off; off >>= 1) s += __shfl_down(s, off);
  if (lane == 0) S[gid] = s;
}

__global__ __launch_bounds__(1024) void small_scan(
    const float* __restrict__ Sg, __bf16* __restrict__ wrelu, float* __restrict__ rowsum) {
  int b = blockIdx.x, tid = threadIdx.x;
  __shared__ float S[32][33];
  int m = tid >> 5, j = tid & 31;
  S[m][j] = Sg[b * 1024 + tid];
  __syncthreads();
  if (tid < 32) {
    float run = 0.f;
    for (int mm = 0; mm < 32; ++mm) { run += S[mm][tid]; S[mm][tid] = run; }
  }
  __syncthreads();
  float v = (j <= m) ? fmaxf(S[m][j], 0.f) : 0.f;
  wrelu[((long)b * 1024 + m) * 1024 + j] = (__bf16)v;
  float rs = v;
#pragma unroll
  for (int off = 16; off; off >>= 1) rs += __shfl_down(rs, off, 32);
  if (j == 0) rowsum[b * 1024 + m] = rs;
}

// ---------------------------------------------------------------------------
extern "C" void kernel_launch(void* const* d_in, const int* in_sizes, int n_in,
                              void* d_out, int out_size, void* d_ws, size_t ws_size,
                              hipStream_t stream) {
  const float* x   = (const float*)d_in[0];
  const float* gen = (const float*)d_in[1];
  const float* Wq  = (const float*)d_in[2];
  const float* Wv  = (const float*)d_in[3];
  const float* Wc  = (const float*)d_in[4];

  char* ws = (char*)d_ws;
  __bf16* xb    = (__bf16*)(ws + 0L);
  __bf16* vT    = (__bf16*)(ws + 33554432L);
  __bf16* Smat  = (__bf16*)(ws + 67108864L);   // gathered scores, 32 MiB
  __bf16* wrelu = (__bf16*)(ws + 134217728L);
  __bf16* genT  = (__bf16*)(ws + 167772160L);
  __bf16* wqT   = (__bf16*)(ws + 169869312L);
  __bf16* wvT   = (__bf16*)(ws + 170393600L);
  __bf16* wcb   = (__bf16*)(ws + 170917888L);
  float*  g2t   = (float*)(ws + 171442176L);
  // overlays in the free region at 16 MiB:
  float*  csum  = (float*)(ws + 16777216L);            // 4 MiB (16*64*1024 f32)
  float*  rsum  = (float*)(ws + 16777216L + 4194304L); // 64 KiB
  float*  Sbuf  = (float*)(ws + 16777216L + 4259840L); // 64 KiB
  // overlays in the free region at 48 MiB:
  __bf16* Pmat  = (__bf16*)(ws + 50331648L);           // 512x512 bf16 (Wc@Wv)
  __bf16* Bg    = (__bf16*)(ws + 51380224L);           // 2048x512 bf16 (gen^T@Wq^T)
  float*  gp    = (float*)(ws + 58720256L);            // 1 MiB g2t partials

  // merged prep: transposes + f2bf (Wc, x) + genT + g2t partials
  prep_kernel<<<11128, 256, 0, stream>>>(x, gen, Wq, Wv, Wc, xb, genT, wqT, wvT, wcb, gp);
  g2t_reduce<<<126, 256, 0, stream>>>(gp, g2t);

  // merged weight folding: Pmat = wcb@wvT^T ; Bg = genT@wqT^T
  gemm_fold<<<80, 256, 0, stream>>>(wcb, wvT, Pmat, genT, wqT, Bg);

  // merged: gathered S = band(x@Bg^T) ; vT = (x@P^T)^T   (256x128 tile, 3-deep)
  gemm_x<<<896, 512, 0, stream>>>(xb, Bg, Pmat, Smat, vT);

  // cumsum + relu/tril + fused rowsum (64 chunks of 16; chunk_sums zeros rsum)
  chunk_sums<<<dim3(64, 16), 128, 0, stream>>>(Smat, csum, rsum);
  scan_kernel<<<64, 256, 0, stream>>>(csum);
  cumsum_relu<<<dim3(64, 16), 128, 0, stream>>>(Smat, csum, wrelu, rsum);

  // exact f32 fix for rows l<32
  small_dots<<<4096, 256, 0, stream>>>(x, g2t, Sbuf);
  small_scan<<<16, 1024, 0, stream>>>(Sbuf, wrelu, rsum);

  // OUT = normalize(Wrelu) @ vc  (batched, triangular) -> f32 d_out directly
  gemm_out<<<dim3(4, 8, 16), 256, 0, stream>>>(wrelu, vT, (float*)d_out, rsum);
}